// Round 1
// baseline (529.550 us; speedup 1.0000x reference)
//
#include <hip/hip_runtime.h>
#include <hip/hip_bf16.h>
#include <stdint.h>

#define N_NODES 100000
#define N_EDGES 1638400
#define IN_FEAT 128
#define OUT_FEAT 64
#define NUM_RELS 8

typedef __attribute__((ext_vector_type(8))) short short8;
typedef __attribute__((ext_vector_type(4))) float floatx4;

__device__ __forceinline__ unsigned short f2bf(float x) {
    union { float f; uint32_t u; } c; c.f = x;
    uint32_t u = c.u;
    u += 0x7FFFu + ((u >> 16) & 1u);   // RNE
    return (unsigned short)(u >> 16);
}
__device__ __forceinline__ float bf2f(unsigned short v) {
    union { uint32_t u; float f; } c; c.u = ((uint32_t)v) << 16;
    return c.f;
}

// ---------------- phase 1: xw[r][n][o] = feat[n][:] . W[r][o][:]  (bf16 out) --
// block = 256 thr (4 waves); blockIdx.x = r, blockIdx.y = node tile of 64.
// LDS rows padded 128->136 bf16 (272 B stride, bank-stride 4 -> 2-way = free).
__global__ __launch_bounds__(256)
void transform_kernel(const float* __restrict__ feat, const float* __restrict__ W,
                      unsigned short* __restrict__ xw) {
    const int r    = blockIdx.x;
    const int n0   = blockIdx.y * 64;
    const int t    = threadIdx.x;
    const int lane = t & 63;
    const int wave = t >> 6;

    __shared__ unsigned short sA[64 * 136];
    __shared__ unsigned short sB[64 * 136];

    // stage feat tile: 2048 float4, 8 per thread, coalesced
    #pragma unroll
    for (int i = 0; i < 8; ++i) {
        int f4 = t + 256 * i;            // 0..2047
        int row = f4 >> 5, c4 = f4 & 31;
        int n = n0 + row;
        float4 v = (n < N_NODES) ? *(const float4*)(feat + (size_t)n * IN_FEAT + c4 * 4)
                                 : make_float4(0.f, 0.f, 0.f, 0.f);
        unsigned short* d = &sA[row * 136 + c4 * 4];
        d[0] = f2bf(v.x); d[1] = f2bf(v.y); d[2] = f2bf(v.z); d[3] = f2bf(v.w);
    }
    // stage W_r tile (64 x 128)
    const float* Wr = W + (size_t)r * OUT_FEAT * IN_FEAT;
    #pragma unroll
    for (int i = 0; i < 8; ++i) {
        int f4 = t + 256 * i;
        int row = f4 >> 5, c4 = f4 & 31;
        float4 v = *(const float4*)(Wr + row * IN_FEAT + c4 * 4);
        unsigned short* d = &sB[row * 136 + c4 * 4];
        d[0] = f2bf(v.x); d[1] = f2bf(v.y); d[2] = f2bf(v.z); d[3] = f2bf(v.w);
    }
    __syncthreads();

    const int quad = lane >> 4;
    const int lrow = lane & 15;
    floatx4 acc[4] = {{0,0,0,0},{0,0,0,0},{0,0,0,0},{0,0,0,0}};
    #pragma unroll
    for (int kk = 0; kk < 4; ++kk) {
        int fofs = kk * 32 + quad * 8;
        short8 a = *(const short8*)&sA[(wave * 16 + lrow) * 136 + fofs];
        #pragma unroll
        for (int j = 0; j < 4; ++j) {
            short8 b = *(const short8*)&sB[(j * 16 + lrow) * 136 + fofs];
            acc[j] = __builtin_amdgcn_mfma_f32_16x16x32_bf16(a, b, acc[j], 0, 0, 0);
        }
    }
    // C/D: row = quad*4+i (node), col = lane&15 (o)
    #pragma unroll
    for (int j = 0; j < 4; ++j) {
        #pragma unroll
        for (int i = 0; i < 4; ++i) {
            int n = n0 + wave * 16 + quad * 4 + i;
            if (n < N_NODES) {
                int o = j * 16 + lrow;
                xw[((size_t)r * N_NODES + n) * OUT_FEAT + o] = f2bf(acc[j][i]);
            }
        }
    }
}

// ---------------- phase 2a: zero offsets -------------------------------------
__global__ void zero_kernel(int* __restrict__ p, int n) {
    int i = blockIdx.x * 256 + threadIdx.x;
    if (i < n) p[i] = 0;
}

// ---------------- phase 2b: degree histogram into offs[d+1] ------------------
__global__ void hist_kernel(const int* __restrict__ dst, int* __restrict__ offs) {
    int e = blockIdx.x * 256 + threadIdx.x;
    if (e < N_EDGES) atomicAdd(&offs[dst[e] + 1], 1);
}

// ---------------- phase 2c: single-block inclusive scan ----------------------
// offs[i] becomes start(i); also cursor[i] = start(i) for the scatter pass.
__global__ __launch_bounds__(1024)
void scan_kernel(int* __restrict__ offs, int* __restrict__ cursor) {
    __shared__ int ws[16];
    __shared__ int sTot;
    const int t = threadIdx.x;
    const int lane = t & 63, wv = t >> 6;
    int carry = 0;
    const int total = N_NODES + 1;
    for (int base = 0; base < total; base += 1024) {
        int idx = base + t;
        int v = (idx < total) ? offs[idx] : 0;
        #pragma unroll
        for (int d = 1; d < 64; d <<= 1) {
            int tv = __shfl_up(v, d, 64);
            if (lane >= d) v += tv;
        }
        if (lane == 63) ws[wv] = v;
        __syncthreads();
        if (wv == 0) {
            int w = (lane < 16) ? ws[lane] : 0;
            #pragma unroll
            for (int d = 1; d < 16; d <<= 1) {
                int tv = __shfl_up(w, d, 64);
                if (lane >= d) w += tv;
            }
            if (lane < 16) ws[lane] = w;
            if (lane == 15) sTot = w;
        }
        __syncthreads();
        int waveOfs = (wv > 0) ? ws[wv - 1] : 0;
        int incl = v + waveOfs + carry;
        if (idx < total) {
            offs[idx] = incl;
            if (idx < N_NODES) cursor[idx] = incl;
        }
        carry += sTot;
        __syncthreads();
    }
}

// ---------------- phase 2d: scatter edges into dst-sorted order --------------
__global__ void scatter_kernel(const int* __restrict__ src, const int* __restrict__ dst,
                               const int* __restrict__ typ, int* __restrict__ cursor,
                               int* __restrict__ sorted) {
    int e = blockIdx.x * 256 + threadIdx.x;
    if (e < N_EDGES) {
        int d = dst[e];
        int pos = atomicAdd(&cursor[d], 1);
        sorted[pos] = (typ[e] << 20) | src[e];   // src < 2^17, rel < 2^3
    }
}

// ---------------- phase 3: per-node gather + reduce (no atomics) -------------
// one wave per dst node; lane = output channel o.
__global__ __launch_bounds__(256)
void gather_kernel(const unsigned short* __restrict__ xw, const int* __restrict__ offs,
                   const int* __restrict__ sorted, float* __restrict__ out) {
    const int wv = threadIdx.x >> 6;
    const int lane = threadIdx.x & 63;
    const int node = blockIdx.x * 4 + wv;
    if (node >= N_NODES) return;
    const int start = offs[node], end = offs[node + 1];
    float acc = 0.f;
    #pragma unroll 4
    for (int e = start; e < end; ++e) {
        int p = sorted[e];                       // broadcast load
        int rel = p >> 20;
        int src = p & 0xFFFFF;
        acc += bf2f(xw[((size_t)rel * N_NODES + src) * OUT_FEAT + lane]);
    }
    out[(size_t)node * OUT_FEAT + lane] = acc;   // coalesced, every node written
}

extern "C" void kernel_launch(void* const* d_in, const int* in_sizes, int n_in,
                              void* d_out, int out_size, void* d_ws, size_t ws_size,
                              hipStream_t stream) {
    const float* feat = (const float*)d_in[0];
    const float* W    = (const float*)d_in[1];
    const int* esrc   = (const int*)d_in[2];
    const int* edst   = (const int*)d_in[3];
    const int* etyp   = (const int*)d_in[4];
    float* out = (float*)d_out;

    char* ws = (char*)d_ws;
    unsigned short* xw = (unsigned short*)ws;                 // 102,400,000 B
    size_t ofs = (size_t)NUM_RELS * N_NODES * OUT_FEAT * 2;
    int* offs = (int*)(ws + ofs);  ofs += (size_t)(N_NODES + 1) * 4;
    ofs = (ofs + 255) & ~(size_t)255;
    int* cursor = (int*)(ws + ofs); ofs += (size_t)N_NODES * 4;
    ofs = (ofs + 255) & ~(size_t)255;
    int* sorted = (int*)(ws + ofs);                           // 6,553,600 B

    zero_kernel<<<(N_NODES + 1 + 255) / 256, 256, 0, stream>>>(offs, N_NODES + 1);
    hist_kernel<<<N_EDGES / 256, 256, 0, stream>>>(edst, offs);
    scan_kernel<<<1, 1024, 0, stream>>>(offs, cursor);
    scatter_kernel<<<N_EDGES / 256, 256, 0, stream>>>(esrc, edst, etyp, cursor, sorted);
    dim3 tg(NUM_RELS, (N_NODES + 63) / 64);
    transform_kernel<<<tg, 256, 0, stream>>>(feat, W, xw);
    gather_kernel<<<(N_NODES + 3) / 4, 256, 0, stream>>>(xw, offs, sorted, out);
}

// Round 3
// 354.417 us; speedup vs baseline: 1.4941x; 1.4941x over previous
//
#include <hip/hip_runtime.h>
#include <hip/hip_bf16.h>
#include <stdint.h>

#define N_NODES 100000
#define N_EDGES 1638400
#define IN_FEAT 128
#define OUT_FEAT 64
#define NUM_RELS 8
#define TOTAL (N_NODES + 1)              // offs length
#define NBLK  ((TOTAL + 1023) / 1024)    // 98 scan blocks

typedef __attribute__((ext_vector_type(8))) short short8;
typedef __attribute__((ext_vector_type(4))) short short4v;
typedef __attribute__((ext_vector_type(4))) float floatx4;

__device__ __forceinline__ unsigned short f2bf(float x) {
    union { float f; uint32_t u; } c; c.f = x;
    uint32_t u = c.u;
    u += 0x7FFFu + ((u >> 16) & 1u);   // RNE
    return (unsigned short)(u >> 16);
}
__device__ __forceinline__ float bf2f(unsigned short v) {
    union { uint32_t u; float f; } c; c.u = ((uint32_t)v) << 16;
    return c.f;
}

// ---------------- prep: zero offs[] AND cast W to bf16 -----------------------
#define W8 (NUM_RELS * OUT_FEAT * IN_FEAT / 8)   // 8192 short8 units
__global__ __launch_bounds__(256)
void prep_kernel(const float* __restrict__ W, unsigned short* __restrict__ W_bf,
                 int* __restrict__ offs) {
    int u = blockIdx.x * 256 + threadIdx.x;
    if (u < TOTAL) offs[u] = 0;
    int w = u - TOTAL;
    if (w >= 0 && w < W8) {
        const float* s = W + (size_t)w * 8;
        float4 a = *(const float4*)s, b = *(const float4*)(s + 4);
        short8 v;
        v[0] = f2bf(a.x); v[1] = f2bf(a.y); v[2] = f2bf(a.z); v[3] = f2bf(a.w);
        v[4] = f2bf(b.x); v[5] = f2bf(b.y); v[6] = f2bf(b.z); v[7] = f2bf(b.w);
        *(short8*)(W_bf + (size_t)w * 8) = v;
    }
}

// ---------------- degree histogram into offs[d+1] ----------------------------
__global__ __launch_bounds__(256)
void hist_kernel(const int* __restrict__ dst, int* __restrict__ offs) {
    int e = blockIdx.x * 256 + threadIdx.x;
    if (e < N_EDGES) atomicAdd(&offs[dst[e] + 1], 1);
}

// ---------------- scan pass 1: per-block (1024) inclusive scan ---------------
__global__ __launch_bounds__(1024)
void blockscan_kernel(int* __restrict__ offs, int* __restrict__ partials) {
    __shared__ int ws[16];
    const int t = threadIdx.x, lane = t & 63, wv = t >> 6;
    const int idx = blockIdx.x * 1024 + t;
    int v = (idx < TOTAL) ? offs[idx] : 0;
    #pragma unroll
    for (int d = 1; d < 64; d <<= 1) {
        int tv = __shfl_up(v, d, 64);
        if (lane >= d) v += tv;
    }
    if (lane == 63) ws[wv] = v;
    __syncthreads();
    if (wv == 0) {
        int w = (lane < 16) ? ws[lane] : 0;
        #pragma unroll
        for (int d = 1; d < 16; d <<= 1) {
            int tv = __shfl_up(w, d, 64);
            if (lane >= d) w += tv;
        }
        if (lane < 16) ws[lane] = w;
    }
    __syncthreads();
    int incl = v + ((wv > 0) ? ws[wv - 1] : 0);
    if (idx < TOTAL) offs[idx] = incl;
    if (t == 1023) partials[blockIdx.x] = incl;   // block total (OOB lanes padded 0)
}

// ---------------- scan pass 2: exclusive scan of 98 block totals -------------
__global__ __launch_bounds__(128)
void partialscan_kernel(int* __restrict__ partials) {
    __shared__ int ws[2];
    const int t = threadIdx.x, lane = t & 63, wv = t >> 6;
    int orig = (t < NBLK) ? partials[t] : 0;
    int v = orig;
    #pragma unroll
    for (int d = 1; d < 64; d <<= 1) {
        int tv = __shfl_up(v, d, 64);
        if (lane >= d) v += tv;
    }
    if (lane == 63) ws[wv] = v;
    __syncthreads();
    int incl = v + ((wv > 0) ? ws[0] : 0);
    if (t < NBLK) partials[t] = incl - orig;      // exclusive
}

// ---------------- scan pass 3: add block prefix; init cursor -----------------
__global__ __launch_bounds__(256)
void addoffs_kernel(const int* __restrict__ partials, int* __restrict__ offs,
                    int* __restrict__ cursor) {
    int idx = blockIdx.x * 256 + threadIdx.x;
    if (idx < TOTAL) {
        int v = offs[idx] + partials[idx >> 10];
        offs[idx] = v;                            // offs[i] = start(i); offs[N] = E
        if (idx < N_NODES) cursor[idx] = v;
    }
}

// ---------------- scatter edges into dst-sorted CSR order --------------------
__global__ __launch_bounds__(256)
void scatter_kernel(const int* __restrict__ src, const int* __restrict__ dst,
                    const int* __restrict__ typ, int* __restrict__ cursor,
                    int* __restrict__ sorted) {
    int e = blockIdx.x * 256 + threadIdx.x;
    if (e < N_EDGES) {
        int d = dst[e];
        int pos = atomicAdd(&cursor[d], 1);
        sorted[pos] = (typ[e] << 20) | src[e];    // src < 2^17, rel < 2^3
    }
}

// ---------------- transform: xw[r][n][o]; feat staged ONCE, r-loop inside ----
// block = 256 thr (4 waves); blockIdx.x = node tile of 64.
// LDS rows padded 128->136 bf16 (272 B stride) — conflict-free b128 access.
__global__ __launch_bounds__(256)
void transform_kernel(const float* __restrict__ feat,
                      const unsigned short* __restrict__ W_bf,
                      unsigned short* __restrict__ xw) {
    const int n0   = blockIdx.x * 64;
    const int t    = threadIdx.x;
    const int lane = t & 63;
    const int wave = t >> 6;

    __shared__ unsigned short sA[64 * 136];
    __shared__ unsigned short sB[64 * 136];

    // stage feat tile once: 2048 float4 loads, cast to bf16, 8-B LDS stores
    #pragma unroll
    for (int i = 0; i < 8; ++i) {
        int f4 = t + 256 * i;               // 0..2047
        int row = f4 >> 5, c4 = f4 & 31;
        int n = n0 + row;
        float4 v = (n < N_NODES) ? *(const float4*)(feat + (size_t)n * IN_FEAT + c4 * 4)
                                 : make_float4(0.f, 0.f, 0.f, 0.f);
        short4v p = { (short)f2bf(v.x), (short)f2bf(v.y), (short)f2bf(v.z), (short)f2bf(v.w) };
        *(short4v*)&sA[row * 136 + c4 * 4] = p;
    }

    const int quad = lane >> 4;
    const int lrow = lane & 15;

    for (int r = 0; r < NUM_RELS; ++r) {
        __syncthreads();                    // r=0: sA ready; r>0: sB consumed
        #pragma unroll
        for (int i = 0; i < 4; ++i) {
            int idx = t + 256 * i;
            int row = idx >> 4, c = idx & 15;
            *(short8*)&sB[row * 136 + c * 8] =
                *(const short8*)(W_bf + ((size_t)r * OUT_FEAT + row) * IN_FEAT + c * 8);
        }
        __syncthreads();

        floatx4 acc[4] = {{0,0,0,0},{0,0,0,0},{0,0,0,0},{0,0,0,0}};
        #pragma unroll
        for (int kk = 0; kk < 4; ++kk) {
            int fofs = kk * 32 + quad * 8;
            short8 a = *(const short8*)&sA[(wave * 16 + lrow) * 136 + fofs];
            #pragma unroll
            for (int j = 0; j < 4; ++j) {
                short8 b = *(const short8*)&sB[(j * 16 + lrow) * 136 + fofs];
                acc[j] = __builtin_amdgcn_mfma_f32_16x16x32_bf16(a, b, acc[j], 0, 0, 0);
            }
        }
        // C/D: row = quad*4+i (node), col = lane&15 (o)
        #pragma unroll
        for (int j = 0; j < 4; ++j) {
            #pragma unroll
            for (int i = 0; i < 4; ++i) {
                int n = n0 + wave * 16 + quad * 4 + i;
                if (n < N_NODES) {
                    int o = j * 16 + lrow;
                    xw[((size_t)r * N_NODES + n) * OUT_FEAT + o] = f2bf(acc[j][i]);
                }
            }
        }
    }
}

// ---------------- gather: one wave per dst node, lane = out channel ----------
__global__ __launch_bounds__(256)
void gather_kernel(const unsigned short* __restrict__ xw, const int* __restrict__ offs,
                   const int* __restrict__ sorted, float* __restrict__ out) {
    const int wv = threadIdx.x >> 6;
    const int lane = threadIdx.x & 63;
    const int node = blockIdx.x * 4 + wv;
    if (node >= N_NODES) return;
    const int start = offs[node], end = offs[node + 1];
    float acc = 0.f;
    #pragma unroll 4
    for (int e = start; e < end; ++e) {
        int p = sorted[e];                   // wave-uniform -> broadcast
        int rel = p >> 20;
        int src = p & 0xFFFFF;
        acc += bf2f(xw[((size_t)rel * N_NODES + src) * OUT_FEAT + lane]);
    }
    out[(size_t)node * OUT_FEAT + lane] = acc;   // coalesced; every node written
}

extern "C" void kernel_launch(void* const* d_in, const int* in_sizes, int n_in,
                              void* d_out, int out_size, void* d_ws, size_t ws_size,
                              hipStream_t stream) {
    const float* feat = (const float*)d_in[0];
    const float* W    = (const float*)d_in[1];
    const int* esrc   = (const int*)d_in[2];
    const int* edst   = (const int*)d_in[3];
    const int* etyp   = (const int*)d_in[4];
    float* out = (float*)d_out;

    // ws budget: stay within round-1's proven ~110 MB footprint
    char* ws = (char*)d_ws;
    size_t ofs = 0;
    unsigned short* xw = (unsigned short*)(ws + ofs);
    ofs += (size_t)NUM_RELS * N_NODES * OUT_FEAT * 2;           // 102,400,000
    unsigned short* W_bf = (unsigned short*)(ws + ofs);
    ofs += (size_t)NUM_RELS * OUT_FEAT * IN_FEAT * 2;           // 131,072
    int* offs = (int*)(ws + ofs);
    ofs += (size_t)TOTAL * 4;                                   // 400,004
    ofs = (ofs + 255) & ~(size_t)255;
    int* cursor = (int*)(ws + ofs);
    ofs += (size_t)N_NODES * 4;                                 // 400,000
    ofs = (ofs + 255) & ~(size_t)255;
    int* sorted = (int*)(ws + ofs);
    ofs += (size_t)N_EDGES * 4;                                 // 6,553,600
    int* partials = (int*)(ws + ofs);                           // 392 B  (~109.9 MB total)

    prep_kernel<<<(TOTAL + W8 + 255) / 256, 256, 0, stream>>>(W, W_bf, offs);
    hist_kernel<<<N_EDGES / 256, 256, 0, stream>>>(edst, offs);
    blockscan_kernel<<<NBLK, 1024, 0, stream>>>(offs, partials);
    partialscan_kernel<<<1, 128, 0, stream>>>(partials);
    addoffs_kernel<<<(TOTAL + 255) / 256, 256, 0, stream>>>(partials, offs, cursor);
    scatter_kernel<<<N_EDGES / 256, 256, 0, stream>>>(esrc, edst, etyp, cursor, sorted);
    transform_kernel<<<(N_NODES + 63) / 64, 256, 0, stream>>>(feat, W_bf, xw);
    gather_kernel<<<(N_NODES + 3) / 4, 256, 0, stream>>>(xw, offs, sorted, out);
}

// Round 4
// 240.428 us; speedup vs baseline: 2.2025x; 1.4741x over previous
//
#include <hip/hip_runtime.h>
#include <hip/hip_bf16.h>
#include <stdint.h>

#define N_NODES 100000
#define N_EDGES 1638400
#define IN_FEAT 128
#define OUT_FEAT 64
#define NUM_RELS 8

#define BUCKET_BITS 9
#define BUCKET_SIZE 512                       // nodes per bucket
#define NBUCKETS ((N_NODES + BUCKET_SIZE - 1) / BUCKET_SIZE)   // 196
#define ABLOCKS 200
#define AEDGES (N_EDGES / ABLOCKS)            // 8192 edges per bin block
#define APT (AEDGES / 1024)                   // 8 edges per thread
#define BK 12                                 // sortB: max 12288 edges/bucket (mean 8389, sigma 92)

// packed edge: src [0:16], rel [17:19], local-dst [20:28]
typedef __attribute__((ext_vector_type(8))) short short8;
typedef __attribute__((ext_vector_type(4))) short short4v;
typedef __attribute__((ext_vector_type(4))) float floatx4;

__device__ __forceinline__ unsigned short f2bf(float x) {
    union { float f; uint32_t u; } c; c.f = x;
    uint32_t u = c.u;
    u += 0x7FFFu + ((u >> 16) & 1u);   // RNE
    return (unsigned short)(u >> 16);
}
__device__ __forceinline__ float bf2f(unsigned short v) {
    union { uint32_t u; float f; } c; c.u = ((uint32_t)v) << 16;
    return c.f;
}

// ---------------- prep: zero bucketHist + cast W to bf16 ---------------------
#define W8 (NUM_RELS * OUT_FEAT * IN_FEAT / 8)   // 8192 short8 units
__global__ __launch_bounds__(256)
void prep_kernel(const float* __restrict__ W, unsigned short* __restrict__ W_bf,
                 int* __restrict__ bucketHist) {
    int u = blockIdx.x * 256 + threadIdx.x;
    if (u < NBUCKETS) bucketHist[u] = 0;
    int w = u - NBUCKETS;
    if (w >= 0 && w < W8) {
        const float* s = W + (size_t)w * 8;
        float4 a = *(const float4*)s, b = *(const float4*)(s + 4);
        short8 v;
        v[0] = f2bf(a.x); v[1] = f2bf(a.y); v[2] = f2bf(a.z); v[3] = f2bf(a.w);
        v[4] = f2bf(b.x); v[5] = f2bf(b.y); v[6] = f2bf(b.z); v[7] = f2bf(b.w);
        *(short8*)(W_bf + (size_t)w * 8) = v;
    }
}

// ---------------- A0: bucket histogram (LDS-staged) --------------------------
__global__ __launch_bounds__(1024)
void buckethist_kernel(const int* __restrict__ dst, int* __restrict__ bucketHist) {
    __shared__ int h[NBUCKETS];
    const int t = threadIdx.x;
    if (t < NBUCKETS) h[t] = 0;
    __syncthreads();
    #pragma unroll
    for (int i = 0; i < APT; ++i) {
        int e = blockIdx.x * AEDGES + i * 1024 + t;
        atomicAdd(&h[dst[e] >> BUCKET_BITS], 1);
    }
    __syncthreads();
    if (t < NBUCKETS && h[t] > 0) atomicAdd(&bucketHist[t], h[t]);
}

// ---------------- A1: scan 196 bucket totals (1 block) -----------------------
__global__ __launch_bounds__(256)
void bucketscan_kernel(const int* __restrict__ bucketHist, int* __restrict__ bucketStart,
                       int* __restrict__ bucketCursor, int* __restrict__ offs) {
    __shared__ int wtot[4];
    const int t = threadIdx.x, lane = t & 63, wv = t >> 6;
    int v = (t < NBUCKETS) ? bucketHist[t] : 0;
    int x = v;
    #pragma unroll
    for (int d = 1; d < 64; d <<= 1) {
        int tv = __shfl_up(x, d, 64);
        if (lane >= d) x += tv;
    }
    if (lane == 63) wtot[wv] = x;
    __syncthreads();
    if (t == 0) {
        int run = 0;
        #pragma unroll
        for (int j = 0; j < 4; ++j) { int c = wtot[j]; wtot[j] = run; run += c; }
    }
    __syncthreads();
    int excl = x - v + wtot[wv];
    if (t < NBUCKETS) { bucketStart[t] = excl; bucketCursor[t] = excl; }
    if (t == 0) { bucketStart[NBUCKETS] = N_EDGES; offs[N_NODES] = N_EDGES; }
}

// ---------------- A2: bin edges into exact bucket regions --------------------
// Per-edge atomics are LDS; one global atomic per (block,bucket) to reserve.
__global__ __launch_bounds__(1024)
void bin_kernel(const int* __restrict__ src, const int* __restrict__ dst,
                const int* __restrict__ typ, int* __restrict__ bucketCursor,
                uint32_t* __restrict__ bins) {
    __shared__ int h[NBUCKETS];
    __shared__ int base[NBUCKETS];
    const int t = threadIdx.x;
    if (t < NBUCKETS) h[t] = 0;
    __syncthreads();
    uint32_t pk[APT]; int bk[APT], rk[APT];
    #pragma unroll
    for (int i = 0; i < APT; ++i) {
        int e = blockIdx.x * AEDGES + i * 1024 + t;
        int d = dst[e];
        int b = d >> BUCKET_BITS;
        bk[i] = b;
        pk[i] = ((uint32_t)(d & (BUCKET_SIZE - 1)) << 20) | ((uint32_t)typ[e] << 17) | (uint32_t)src[e];
        rk[i] = atomicAdd(&h[b], 1);
    }
    __syncthreads();
    if (t < NBUCKETS && h[t] > 0) base[t] = atomicAdd(&bucketCursor[t], h[t]);
    __syncthreads();
    #pragma unroll
    for (int i = 0; i < APT; ++i)
        bins[base[bk[i]] + rk[i]] = pk[i];
}

// ---------------- A3: per-bucket counting sort (in place) + CSR offs ---------
__global__ __launch_bounds__(1024)
void sortb_kernel(const int* __restrict__ bucketStart, uint32_t* __restrict__ bins,
                  int* __restrict__ offs) {
    __shared__ int cnt_l[BUCKET_SIZE];
    __shared__ int start_l[BUCKET_SIZE];
    __shared__ int wtot[8];
    const int b = blockIdx.x;
    const int t = threadIdx.x, lane = t & 63, wv = t >> 6;
    const int s = bucketStart[b];
    const int cnt = bucketStart[b + 1] - s;
    if (t < BUCKET_SIZE) cnt_l[t] = 0;
    __syncthreads();
    uint32_t pk[BK]; int rk[BK], ld[BK];
    #pragma unroll
    for (int k = 0; k < BK; ++k) {
        int idx = t + k * 1024;
        ld[k] = -1;
        if (idx < cnt) {
            uint32_t p = bins[s + idx];
            pk[k] = p;
            ld[k] = (int)(p >> 20);
            rk[k] = atomicAdd(&cnt_l[ld[k]], 1);
        }
    }
    __syncthreads();
    // exclusive scan of cnt_l[512] with first 8 waves
    int v = 0, x = 0;
    if (t < BUCKET_SIZE) {
        v = cnt_l[t]; x = v;
        #pragma unroll
        for (int d = 1; d < 64; d <<= 1) {
            int tv = __shfl_up(x, d, 64);
            if (lane >= d) x += tv;
        }
        if (lane == 63) wtot[wv] = x;
    }
    __syncthreads();
    if (t == 0) {
        int run = 0;
        #pragma unroll
        for (int j = 0; j < 8; ++j) { int c = wtot[j]; wtot[j] = run; run += c; }
    }
    __syncthreads();
    if (t < BUCKET_SIZE) {
        int excl = x - v + wtot[wv];
        start_l[t] = excl;
        int node = b * BUCKET_SIZE + t;
        if (node < N_NODES) offs[node] = s + excl;
    }
    __syncthreads();
    #pragma unroll
    for (int k = 0; k < BK; ++k)
        if (ld[k] >= 0)
            bins[s + start_l[ld[k]] + rk[k]] = pk[k];
}

// ---------------- transform: xw[r][n][o]; feat staged ONCE, r-loop inside ----
__global__ __launch_bounds__(256)
void transform_kernel(const float* __restrict__ feat,
                      const unsigned short* __restrict__ W_bf,
                      unsigned short* __restrict__ xw) {
    const int n0   = blockIdx.x * 64;
    const int t    = threadIdx.x;
    const int lane = t & 63;
    const int wave = t >> 6;

    __shared__ unsigned short sA[64 * 136];
    __shared__ unsigned short sB[64 * 136];

    #pragma unroll
    for (int i = 0; i < 8; ++i) {
        int f4 = t + 256 * i;               // 0..2047
        int row = f4 >> 5, c4 = f4 & 31;
        int n = n0 + row;
        float4 v = (n < N_NODES) ? *(const float4*)(feat + (size_t)n * IN_FEAT + c4 * 4)
                                 : make_float4(0.f, 0.f, 0.f, 0.f);
        short4v p = { (short)f2bf(v.x), (short)f2bf(v.y), (short)f2bf(v.z), (short)f2bf(v.w) };
        *(short4v*)&sA[row * 136 + c4 * 4] = p;
    }

    const int quad = lane >> 4;
    const int lrow = lane & 15;

    for (int r = 0; r < NUM_RELS; ++r) {
        __syncthreads();
        #pragma unroll
        for (int i = 0; i < 4; ++i) {
            int idx = t + 256 * i;
            int row = idx >> 4, c = idx & 15;
            *(short8*)&sB[row * 136 + c * 8] =
                *(const short8*)(W_bf + ((size_t)r * OUT_FEAT + row) * IN_FEAT + c * 8);
        }
        __syncthreads();

        floatx4 acc[4] = {{0,0,0,0},{0,0,0,0},{0,0,0,0},{0,0,0,0}};
        #pragma unroll
        for (int kk = 0; kk < 4; ++kk) {
            int fofs = kk * 32 + quad * 8;
            short8 a = *(const short8*)&sA[(wave * 16 + lrow) * 136 + fofs];
            #pragma unroll
            for (int j = 0; j < 4; ++j) {
                short8 bb = *(const short8*)&sB[(j * 16 + lrow) * 136 + fofs];
                acc[j] = __builtin_amdgcn_mfma_f32_16x16x32_bf16(a, bb, acc[j], 0, 0, 0);
            }
        }
        #pragma unroll
        for (int j = 0; j < 4; ++j) {
            #pragma unroll
            for (int i = 0; i < 4; ++i) {
                int n = n0 + wave * 16 + quad * 4 + i;
                if (n < N_NODES) {
                    int o = j * 16 + lrow;
                    xw[((size_t)r * N_NODES + n) * OUT_FEAT + o] = f2bf(acc[j][i]);
                }
            }
        }
    }
}

// ---------------- gather: one wave per dst node, lane = out channel ----------
__global__ __launch_bounds__(256)
void gather_kernel(const unsigned short* __restrict__ xw, const int* __restrict__ offs,
                   const uint32_t* __restrict__ bins, float* __restrict__ out) {
    const int wv = threadIdx.x >> 6;
    const int lane = threadIdx.x & 63;
    const int node = blockIdx.x * 4 + wv;
    if (node >= N_NODES) return;
    const int start = offs[node], end = offs[node + 1];
    float acc = 0.f;
    #pragma unroll 4
    for (int e = start; e < end; ++e) {
        uint32_t p = bins[e];                // wave-uniform -> broadcast
        int rel = (p >> 17) & 7;
        int src = p & 0x1FFFF;
        acc += bf2f(xw[((size_t)rel * N_NODES + src) * OUT_FEAT + lane]);
    }
    out[(size_t)node * OUT_FEAT + lane] = acc;   // coalesced; every node written
}

extern "C" void kernel_launch(void* const* d_in, const int* in_sizes, int n_in,
                              void* d_out, int out_size, void* d_ws, size_t ws_size,
                              hipStream_t stream) {
    const float* feat = (const float*)d_in[0];
    const float* W    = (const float*)d_in[1];
    const int* esrc   = (const int*)d_in[2];
    const int* edst   = (const int*)d_in[3];
    const int* etyp   = (const int*)d_in[4];
    float* out = (float*)d_out;

    // ws layout (~109.5 MB, within round-1's proven 109.8 MB footprint)
    char* ws = (char*)d_ws;
    size_t ofs = 0;
    unsigned short* xw = (unsigned short*)(ws + ofs);
    ofs += (size_t)NUM_RELS * N_NODES * OUT_FEAT * 2;           // 102,400,000
    unsigned short* W_bf = (unsigned short*)(ws + ofs);
    ofs += (size_t)NUM_RELS * OUT_FEAT * IN_FEAT * 2;           // 131,072
    uint32_t* bins = (uint32_t*)(ws + ofs);
    ofs += (size_t)N_EDGES * 4;                                 // 6,553,600
    int* offs = (int*)(ws + ofs);
    ofs += ((size_t)(N_NODES + 1) * 4 + 255) & ~(size_t)255;    // 400,128
    int* bucketHist = (int*)(ws + ofs);   ofs += 1024;
    int* bucketStart = (int*)(ws + ofs);  ofs += 1024;          // NBUCKETS+1 ints
    int* bucketCursor = (int*)(ws + ofs); ofs += 1024;

    prep_kernel<<<(NBUCKETS + W8 + 255) / 256, 256, 0, stream>>>(W, W_bf, bucketHist);
    buckethist_kernel<<<ABLOCKS, 1024, 0, stream>>>(edst, bucketHist);
    bucketscan_kernel<<<1, 256, 0, stream>>>(bucketHist, bucketStart, bucketCursor, offs);
    bin_kernel<<<ABLOCKS, 1024, 0, stream>>>(esrc, edst, etyp, bucketCursor, bins);
    sortb_kernel<<<NBUCKETS, 1024, 0, stream>>>(bucketStart, bins, offs);
    transform_kernel<<<(N_NODES + 63) / 64, 256, 0, stream>>>(feat, W_bf, xw);
    gather_kernel<<<(N_NODES + 3) / 4, 256, 0, stream>>>(xw, offs, bins, out);
}